// Round 6
// baseline (246.199 us; speedup 1.0000x reference)
//
#include <hip/hip_runtime.h>

// ---------------------------------------------------------------------------
// CrossAttention: B=8, T=S=1024, E=H=768, fp32 in/out, bf16 MFMA internally.
//
// Round 15: r14 fusion + sched_barrier(0) ordering pins in pv_gemm.
// r14 failed correctness; audit found no addressing/math error vs the
// verified r13 path. Documented failure mode (m214 r263 / lesson #18): the
// compiler moves plain LDS stores/loads across raw s_waitcnt/s_barrier
// builtins. r9's DMA-only pipeline was immune (intrinsic writes are opaque);
// r14's reg-staged WRITEA introduced plain ds_writes. Fix: pin program order
// with __builtin_amdgcn_sched_barrier(0) at every sync edge + volatile
// WRITEA stores. Everything else identical to r14:
//  - scores_gemm epilogue emits per-(row,64col) softmax partials (max,sumexp)
//  - softmax_rows removed; pv_gemm applies exp on the fly (reg-staged A)
//  - prep = convert_inputs + transpose_w fused
// ---------------------------------------------------------------------------

typedef __bf16 bf16x8 __attribute__((ext_vector_type(8)));
typedef float  f32x4  __attribute__((ext_vector_type(4)));

#define WAIT_VM8   __builtin_amdgcn_s_waitcnt(0x0F78)   // vmcnt(8)
#define WAIT_VM12  __builtin_amdgcn_s_waitcnt(0x0F7C)   // vmcnt(12)
#define WAIT_VM0   __builtin_amdgcn_s_waitcnt(0x0F70)   // vmcnt(0)
#define WAIT_LGKM0 __builtin_amdgcn_s_waitcnt(0xC07F)   // lgkmcnt(0), vm nowait
#define BAR        __builtin_amdgcn_s_barrier()
#define SBAR0      __builtin_amdgcn_sched_barrier(0)

__device__ __forceinline__ unsigned short f2bf(float f) {
    unsigned int u = __float_as_uint(f);
    u += 0x7fffu + ((u >> 16) & 1u);   // RNE; inputs are finite
    return (unsigned short)(u >> 16);
}

__device__ __forceinline__ void async_copy16(const void* g, void* s) {
    __builtin_amdgcn_global_load_lds(
        (const __attribute__((address_space(1))) void*)g,
        (__attribute__((address_space(3))) void*)s, 16, 0, 0);
}

// Block computes C[row0:row0+128, col0:col0+128].
// Ag = A + row0*K ([*,K] bf16 row-major); Bg = B^T + col0*K ([*,K]).
// Exactly one of Cf/Cb non-null. transC: store C^T as [b][H][S] (vt).
// statsp (optional): per-(row,64col) softmax partials, pre-offset to row0.
__device__ __forceinline__ void gemm_core(
    const unsigned short* __restrict__ Ag,
    const unsigned short* __restrict__ Bg,
    const int K,
    float* __restrict__ Cf, unsigned short* __restrict__ Cb,
    const long ldc, const int transC, const float* __restrict__ bias,
    const float scale, const long row0, const long col0,
    float2* __restrict__ statsp)
{
    __shared__ __align__(16) unsigned short As0[8192];   // [128][64] swizzled
    __shared__ __align__(16) unsigned short As1[8192];
    __shared__ __align__(16) unsigned short Bs0[8192];
    __shared__ __align__(16) unsigned short Bs1[8192];

    const int tid  = threadIdx.x;
    const int lane = tid & 63;
    const int quad = lane >> 4;
    const int l16  = lane & 15;
    const int wv   = tid >> 6;
    const int wm   = (wv >> 1) * 64;
    const int wn   = (wv & 1) * 64;

    const int j8 = ((lane & 7) ^ ((lane >> 3) & 7)) * 8;   // src k-offset, elems
    const int rb = wv * 32 + (lane >> 3);                  // row for h=0
    const unsigned short* sa_src = Ag + (long)rb * K + j8;
    const unsigned short* sb_src = Bg + (long)rb * K + j8;
    const int dbase = (wv * 256 + lane) * 8;               // LDS dst elems, h=0

    f32x4 acc[4][4];
#pragma unroll
    for (int i = 0; i < 4; ++i)
#pragma unroll
        for (int j = 0; j < 4; ++j)
            acc[i][j] = f32x4{0.f, 0.f, 0.f, 0.f};

    auto stage = [&](unsigned short* dA, unsigned short* dB, int k0) {
#pragma unroll
        for (int h = 0; h < 4; ++h) {
            async_copy16(sa_src + (long)(h * 8) * K + k0, &dA[dbase + h * 512]);
            async_copy16(sb_src + (long)(h * 8) * K + k0, &dB[dbase + h * 512]);
        }
    };

    auto compute = [&](const unsigned short* sA, const unsigned short* sB) {
#pragma unroll
        for (int h = 0; h < 2; ++h) {
            bf16x8 af[4], bf[4];
            const int sl = ((quad + h * 4) ^ (l16 & 7)) * 8;
#pragma unroll
            for (int i = 0; i < 4; ++i) {
                af[i] = *(const bf16x8*)&sA[(wm + i * 16 + l16) * 64 + sl];
                bf[i] = *(const bf16x8*)&sB[(wn + i * 16 + l16) * 64 + sl];
            }
#pragma unroll
            for (int i = 0; i < 4; ++i)
#pragma unroll
                for (int j = 0; j < 4; ++j)
                    acc[i][j] = __builtin_amdgcn_mfma_f32_16x16x32_bf16(
                        af[i], bf[j], acc[i][j], 0, 0, 0);
        }
    };

    const int nk = K >> 6;            // 12 or 16: even, >= 4
    stage(As0, Bs0, 0);
    stage(As1, Bs1, 64);
    int k0 = 128;

    for (int t = 0; t < nk - 2; t += 2) {
        WAIT_VM8; BAR;
        compute(As0, Bs0);
        BAR;
        stage(As0, Bs0, k0); k0 += 64;

        WAIT_VM8; BAR;
        compute(As1, Bs1);
        BAR;
        stage(As1, Bs1, k0); k0 += 64;
    }
    WAIT_VM8; BAR;
    compute(As0, Bs0);
    WAIT_VM0; BAR;
    compute(As1, Bs1);

    // epilogue: C/D layout col=lane&15, row=quad*4+reg  [m89/m91 verified]
#pragma unroll
    for (int i = 0; i < 4; ++i) {
#pragma unroll
        for (int j = 0; j < 4; ++j) {
            const long r0 = row0 + wm + i * 16 + quad * 4;
            const long c  = col0 + wn + j * 16 + l16;
            const float bb = bias ? bias[c] : 0.0f;
#pragma unroll
            for (int r = 0; r < 4; ++r) {
                const float v = acc[i][j][r] * scale + bb;
                const long rr = r0 + r;
                if (Cb) {
                    if (transC) {
                        Cb[((rr >> 10) * 768 + c) * 1024 + (rr & 1023)] = f2bf(v);
                    } else {
                        Cb[rr * ldc + c] = f2bf(v);
                    }
                } else {
                    Cf[rr * ldc + c] = v;
                }
            }
        }
    }

    // optional softmax partials over this wave's 64-col half (scores only)
    if (statsp) {
        const int ct = (int)((col0 + wn) >> 6);
#pragma unroll
        for (int i = 0; i < 4; ++i) {
#pragma unroll
            for (int r = 0; r < 4; ++r) {
                const float v0 = acc[i][0][r] * scale, v1 = acc[i][1][r] * scale;
                const float v2 = acc[i][2][r] * scale, v3 = acc[i][3][r] * scale;
                float mx = fmaxf(fmaxf(v0, v1), fmaxf(v2, v3));
                mx = fmaxf(mx, __shfl_xor(mx, 1));
                mx = fmaxf(mx, __shfl_xor(mx, 2));
                mx = fmaxf(mx, __shfl_xor(mx, 4));
                mx = fmaxf(mx, __shfl_xor(mx, 8));
                float sm = __expf(v0 - mx) + __expf(v1 - mx) +
                           __expf(v2 - mx) + __expf(v3 - mx);
                sm += __shfl_xor(sm, 1);
                sm += __shfl_xor(sm, 2);
                sm += __shfl_xor(sm, 4);
                sm += __shfl_xor(sm, 8);
                if (l16 == 0)
                    statsp[(wm + i * 16 + quad * 4 + r) * 16 + ct] =
                        make_float2(mx, sm);
            }
        }
    }
}

// ---------------------------------------------------------------------------
// XCD-locality mapping (HW round-robins consecutive blockIdx.x over 8 XCDs).

__global__ __launch_bounds__(256, 2) void proj_qkv(
    const unsigned short* __restrict__ xb, const unsigned short* __restrict__ eb,
    const unsigned short* __restrict__ wqt, const unsigned short* __restrict__ wkt,
    const unsigned short* __restrict__ wvt,
    const float* __restrict__ bq, const float* __restrict__ bk,
    const float* __restrict__ bv,
    unsigned short* __restrict__ q, unsigned short* __restrict__ k,
    unsigned short* __restrict__ vt)
{
    const unsigned short *A, *Bt; const float* bias; unsigned short* C;
    int trans = 0;
    switch (blockIdx.z) {
        case 0:  A = xb; Bt = wqt; bias = bq; C = q;  break;
        case 1:  A = eb; Bt = wkt; bias = bk; C = k;  break;
        default: A = eb; Bt = wvt; bias = bv; C = vt; trans = 1; break;
    }
    const int p = blockIdx.x;
    const int g = p & 7, m = p >> 3;          // m in [0,48)
    const long row0 = (long)(g * 8 + (m & 7)) * 128;
    const long col0 = (long)(m >> 3) * 128;
    gemm_core(A + row0 * 768, Bt + col0 * 768, 768,
              nullptr, C, 768, trans, bias, 1.0f, row0, col0, nullptr);
}

__global__ __launch_bounds__(256, 2) void scores_gemm(
    const unsigned short* __restrict__ q, const unsigned short* __restrict__ k,
    float* __restrict__ sc, float2* __restrict__ stats, float scale)
{
    const int p = blockIdx.x;                 // [0,512): batch pinned to XCD
    const long b = p & 7;
    const int m  = p >> 3;                    // [0,64)
    const long row0 = (long)(m & 7) * 128;
    const long col0 = (long)(m >> 3) * 128;
    gemm_core(q + (b * 1024 + row0) * 768, k + b * 786432 + col0 * 768, 768,
              sc + b * 1048576, nullptr, 1024, 0, nullptr, scale, row0, col0,
              stats + (b * 1024 + row0) * 16);
}

// pv: ao[b][t][h] = softmax(sc)[b][t][:] @ v[b][:][h], P computed on the fly.
__global__ __launch_bounds__(256, 2) void pv_gemm(
    const float* __restrict__ sc, const float2* __restrict__ stats,
    const unsigned short* __restrict__ vt, unsigned short* __restrict__ ao)
{
    __shared__ __align__(16) unsigned short As0[8192];   // P tile, swizzled
    __shared__ __align__(16) unsigned short As1[8192];
    __shared__ __align__(16) unsigned short Bs0[8192];
    __shared__ __align__(16) unsigned short Bs1[8192];
    __shared__ float sM[128], sI[128];

    const int p = blockIdx.x;                 // [0,384): batch pinned to XCD
    const long b = p & 7;
    const int m  = p >> 3;                    // [0,48)
    const long row0 = (long)(m & 7) * 128;
    const long col0 = (long)(m >> 3) * 128;

    const float* Sg = sc + (b * 1024 + row0) * 1024;           // [128][1024] f32
    const unsigned short* Bg = vt + b * 786432 + col0 * 1024;  // [128][1024] bf16
    const float2* stg = stats + (b * 1024 + row0) * 16;
    unsigned short* aog = ao + b * 786432;

    const int tid = threadIdx.x;

    // stats prologue: combine 16 per-64col partials -> (M, 1/L) per row
    if (tid < 128) {
        const float2* sp = stg + tid * 16;
        float M = sp[0].x;
#pragma unroll
        for (int j = 1; j < 16; ++j) M = fmaxf(M, sp[j].x);
        float L = 0.f;
#pragma unroll
        for (int j = 0; j < 16; ++j) L += sp[j].y * __expf(sp[j].x - M);
        sM[tid] = M;
        sI[tid] = 1.0f / L;
    }
    __syncthreads();

    const int lane = tid & 63;
    const int quad = lane >> 4;
    const int l16  = lane & 15;
    const int wv   = tid >> 6;
    const int wm   = (wv >> 1) * 64;
    const int wn   = (wv & 1) * 64;
    const int j8   = ((lane & 7) ^ ((lane >> 3) & 7)) * 8;   // elems
    const int rb   = wv * 32 + (lane >> 3);                  // local row, h adds 8
    const unsigned short* sb_src = Bg + (long)rb * 1024 + j8;
    const float*          sa_src = Sg + (long)rb * 1024 + j8;
    const int dbase = (wv * 256 + lane) * 8;

    float Mh[4], Ih[4];
#pragma unroll
    for (int h = 0; h < 4; ++h) { Mh[h] = sM[rb + h * 8]; Ih[h] = sI[rb + h * 8]; }

    f32x4 acc[4][4];
#pragma unroll
    for (int i = 0; i < 4; ++i)
#pragma unroll
        for (int j = 0; j < 4; ++j)
            acc[i][j] = f32x4{0.f, 0.f, 0.f, 0.f};

    f32x4 a0[4][2], a1[4][2];   // named even/odd reg tiles (rule #20)

    auto LOADA = [&](f32x4 (&ar)[4][2], int k0) {   // 8 global_load_dwordx4
#pragma unroll
        for (int h = 0; h < 4; ++h) {
            const float* p4 = sa_src + (long)(h * 8) * 1024 + k0;
            ar[h][0] = *(const f32x4*)(p4);
            ar[h][1] = *(const f32x4*)(p4 + 4);
        }
    };
    auto DMAB = [&](unsigned short* dB, int k0) {   // 4 global_load_lds
#pragma unroll
        for (int h = 0; h < 4; ++h)
            async_copy16(sb_src + (long)(h * 8) * 1024 + k0, &dB[dbase + h * 512]);
    };
    auto WRITEA = [&](unsigned short* dA, f32x4 (&ar)[4][2]) {
#pragma unroll
        for (int h = 0; h < 4; ++h) {
            const float M = Mh[h], I = Ih[h];
            union { unsigned short us[8]; bf16x8 v; } o;
#pragma unroll
            for (int e = 0; e < 4; ++e)
                o.us[e] = f2bf(__expf(ar[h][0][e] - M) * I);
#pragma unroll
            for (int e = 0; e < 4; ++e)
                o.us[4 + e] = f2bf(__expf(ar[h][1][e] - M) * I);
            *(volatile bf16x8*)&dA[dbase + h * 512] = o.v;   // volatile: no IR sink
        }
    };
    auto compute = [&](const unsigned short* sA, const unsigned short* sB) {
#pragma unroll
        for (int h = 0; h < 2; ++h) {
            bf16x8 af[4], bf[4];
            const int sl = ((quad + h * 4) ^ (l16 & 7)) * 8;
#pragma unroll
            for (int i = 0; i < 4; ++i) {
                af[i] = *(const bf16x8*)&sA[(wm + i * 16 + l16) * 64 + sl];
                bf[i] = *(const bf16x8*)&sB[(wn + i * 16 + l16) * 64 + sl];
            }
#pragma unroll
            for (int i = 0; i < 4; ++i)
#pragma unroll
                for (int j = 0; j < 4; ++j)
                    acc[i][j] = __builtin_amdgcn_mfma_f32_16x16x32_bf16(
                        af[i], bf[j], acc[i][j], 0, 0, 0);
        }
    };

    // pipeline: per tile 12 vm ops {8 A-loads -> regs, 4 B-DMA}; 2-deep.
    // sched_barrier(0) pins the program order the sync ledger assumes
    // (lesson #18: plain LDS ops move across raw waitcnt/barrier builtins).
    const int nt = 16;                 // K = 1024
    LOADA(a0, 0);  DMAB(Bs0, 0);       // tile 0
    LOADA(a1, 64); DMAB(Bs1, 64);      // tile 1
    int kk = 128;
#pragma unroll 1
    for (int t = 0; t < nt; t += 2) {
        // ---- tile t (even): a0 / As0 / Bs0 ----
        if (t + 2 < nt) WAIT_VM12; else WAIT_VM0;
        SBAR0;
        WRITEA(As0, a0);
        SBAR0;
        if (t + 2 < nt) LOADA(a0, kk);
        SBAR0;
        WAIT_LGKM0;
        SBAR0;
        BAR;
        SBAR0;
        compute(As0, Bs0);
        SBAR0;
        BAR;
        SBAR0;
        if (t + 2 < nt) DMAB(Bs0, kk);
        kk += 64;
        // ---- tile t+1 (odd): a1 / As1 / Bs1 ----
        if (t + 3 < nt) WAIT_VM12; else WAIT_VM0;
        SBAR0;
        WRITEA(As1, a1);
        SBAR0;
        if (t + 3 < nt) LOADA(a1, kk);
        SBAR0;
        WAIT_LGKM0;
        SBAR0;
        BAR;
        SBAR0;
        compute(As1, Bs1);
        SBAR0;
        BAR;
        SBAR0;
        if (t + 3 < nt) DMAB(Bs1, kk);
        kk += 64;
    }

    // epilogue: bf16 ao[b][row][col]
#pragma unroll
    for (int i = 0; i < 4; ++i) {
#pragma unroll
        for (int j = 0; j < 4; ++j) {
            const long r0 = row0 + wm + i * 16 + quad * 4;
            const long c  = col0 + wn + j * 16 + l16;
#pragma unroll
            for (int r = 0; r < 4; ++r)
                aog[(r0 + r) * 768 + c] = f2bf(acc[i][j][r]);
        }
    }
}

__global__ __launch_bounds__(256, 2) void outproj_gemm(
    const unsigned short* __restrict__ ao, const unsigned short* __restrict__ wpt,
    float* __restrict__ out, const float* __restrict__ bp)
{
    const int p = blockIdx.x;                 // [0,384)
    const int g = p & 7, m = p >> 3;
    const long row0 = (long)(g * 8 + (m & 7)) * 128;
    const long col0 = (long)(m >> 3) * 128;
    gemm_core(ao + row0 * 768, wpt + col0 * 768, 768,
              out, nullptr, 768, 0, bp, 1.0f, row0, col0, nullptr);
}

// ---------------------------------------------------------------------------
// prep: fp32->bf16 conversion of x/enc (blocks 0..12287) + 32x32 bf16
// transposes of the four weights (blocks 12288..14591).

__global__ __launch_bounds__(256) void prep(
    const float* __restrict__ x, const float* __restrict__ enc,
    unsigned short* __restrict__ xb, unsigned short* __restrict__ eb,
    const float* __restrict__ w0, const float* __restrict__ w1,
    const float* __restrict__ w2, const float* __restrict__ w3,
    unsigned short* __restrict__ o0, unsigned short* __restrict__ o1,
    unsigned short* __restrict__ o2, unsigned short* __restrict__ o3)
{
    __shared__ float t[32][33];
    const int bx = blockIdx.x;
    if (bx < 12288) {
        const int i = bx * 256 + threadIdx.x;   // float4 index
        const bool second = (i >= 1572864);
        const int idx = second ? i - 1572864 : i;
        const float4 v = second ? ((const float4*)enc)[idx] : ((const float4*)x)[idx];
        ushort4 o;
        o.x = f2bf(v.x); o.y = f2bf(v.y); o.z = f2bf(v.z); o.w = f2bf(v.w);
        if (second) ((ushort4*)eb)[idx] = o;
        else        ((ushort4*)xb)[idx] = o;
        return;
    }
    const int z  = bx - 12288;                  // 0..2303
    const int wi = z / 576;                     // which weight
    const int tt = z % 576;                     // 24x24 tiles
    const float* w; unsigned short* o;
    switch (wi) {
        case 0:  w = w0; o = o0; break;
        case 1:  w = w1; o = o1; break;
        case 2:  w = w2; o = o2; break;
        default: w = w3; o = o3; break;
    }
    const int tx = threadIdx.x & 31;
    const int ty = threadIdx.x >> 5;            // 0..7
    const int k0 = (tt % 24) * 32;
    const int n0 = (tt / 24) * 32;
#pragma unroll
    for (int i = 0; i < 4; ++i)
        t[ty + i * 8][tx] = w[(long)(k0 + ty + i * 8) * 768 + n0 + tx];
    __syncthreads();
#pragma unroll
    for (int i = 0; i < 4; ++i)
        o[(long)(n0 + ty + i * 8) * 768 + k0 + tx] = f2bf(t[tx][ty + i * 8]);
}

// ---------------------------------------------------------------------------

extern "C" void kernel_launch(void* const* d_in, const int* in_sizes, int n_in,
                              void* d_out, int out_size, void* d_ws, size_t ws_size,
                              hipStream_t stream) {
    const float* x   = (const float*)d_in[0];
    const float* enc = (const float*)d_in[1];
    const float* Wq  = (const float*)d_in[2];
    const float* bq  = (const float*)d_in[3];
    const float* Wk  = (const float*)d_in[4];
    const float* bk  = (const float*)d_in[5];
    const float* Wv  = (const float*)d_in[6];
    const float* bv  = (const float*)d_in[7];
    const float* Wp  = (const float*)d_in[8];
    const float* bp  = (const float*)d_in[9];
    float* out = (float*)d_out;

    // workspace layout (bytes); peak ~96.5 MiB
    char* ws = (char*)d_ws;
    unsigned short* xb  = (unsigned short*)(ws + 0);         // dead after proj
    unsigned short* eb  = (unsigned short*)(ws + 12582912);  // dead after proj
    unsigned short* q   = (unsigned short*)(ws + 25165824);
    unsigned short* k   = (unsigned short*)(ws + 37748736);
    unsigned short* vt  = (unsigned short*)(ws + 50331648);  // [B][H][S]
    unsigned short* wqt = (unsigned short*)(ws + 62914560);
    unsigned short* wkt = (unsigned short*)(ws + 64094208);
    unsigned short* wvt = (unsigned short*)(ws + 65273856);
    unsigned short* wpt = (unsigned short*)(ws + 66453504);
    float*          sc  = (float*)(ws + 67633152);           // 33554432 fp32
    unsigned short* ao  = (unsigned short*)(ws + 0);         // overlays xb (dead)
    float2*        stats = (float2*)(ws + 12582912);         // overlays eb (dead)

    const float scale = 0.03608439182435161f;  // 1/sqrt(768)

    // 1. prep: fp32->bf16 inputs + W^T bf16 (fused)
    prep<<<14592, 256, 0, stream>>>(x, enc, xb, eb, Wq, Wk, Wv, Wp,
                                    wqt, wkt, wvt, wpt);

    // 2. q/k/v projections: 128x128 tiles, XCD-grouped flat grid
    proj_qkv<<<dim3(384, 1, 3), 256, 0, stream>>>(xb, eb, wqt, wkt, wvt,
                                                  bq, bk, bv, q, k, vt);

    // 3. scores = q k^T * scale (fp32) + softmax partials, one batch per XCD
    scores_gemm<<<dim3(512, 1, 1), 256, 0, stream>>>(q, k, sc, stats, scale);

    // 4. ao = softmax(sc) @ V with on-the-fly exp, one batch per XCD
    pv_gemm<<<dim3(384, 1, 1), 256, 0, stream>>>(sc, stats, vt, ao);

    // 5. out = ao @ Wp + bp
    outproj_gemm<<<dim3(384, 1, 1), 256, 0, stream>>>(ao, wpt, out, bp);
}

// Round 7
// 234.560 us; speedup vs baseline: 1.0496x; 1.0496x over previous
//
#include <hip/hip_runtime.h>

// ---------------------------------------------------------------------------
// CrossAttention: B=8, T=S=1024, E=H=768, fp32 in/out, bf16 MFMA internally.
//
// Round 16: m97/m103-exact GEMM structure (the fastest HARNESS-MEASURED
// 128x128 structure on this chip: 874-912 TF at 4096^3).
//   - SINGLE-buffered LDS (16KB A + 16KB B = 32KB/block) -> 4 blocks/CU
//     (launch_bounds(256,4)); cross-block TLP hides staging latency (m114).
//   - per K-step: __syncthreads (drains DMA -> tile landed) ; compute ;
//     __syncthreads (read-done) ; stage(t+1). No raw vmcnt/barrier builtins.
//   - r9's explicit dbuf + counted vmcnt was the documented null (m99/m131-141)
//     and cost half the occupancy. All 6 prior rounds' variants pinned at
//     ~13 B/cyc/CU ingest; m97 sustains ~22 B/cyc/CU with this structure.
// Kept: verified XOR swizzle (0 bank conflicts), XCD-grouped block mapping
// (r13 +3%), fused prep (r15, passed), r13 softmax_rows + workspace.
// ---------------------------------------------------------------------------

typedef __bf16 bf16x8 __attribute__((ext_vector_type(8)));
typedef float  f32x4  __attribute__((ext_vector_type(4)));

__device__ __forceinline__ unsigned short f2bf(float f) {
    unsigned int u = __float_as_uint(f);
    u += 0x7fffu + ((u >> 16) & 1u);   // RNE; inputs are finite
    return (unsigned short)(u >> 16);
}

__device__ __forceinline__ void async_copy16(const void* g, void* s) {
    __builtin_amdgcn_global_load_lds(
        (const __attribute__((address_space(1))) void*)g,
        (__attribute__((address_space(3))) void*)s, 16, 0, 0);
}

// Block computes C[row0:row0+128, col0:col0+128].
// Ag = A + row0*K ([*,K] bf16 row-major); Bg = B^T + col0*K ([*,K]).
// Exactly one of Cf/Cb non-null. transC: store C^T as [b][H][S] (vt).
__device__ __forceinline__ void gemm_core(
    const unsigned short* __restrict__ Ag,
    const unsigned short* __restrict__ Bg,
    const int K,
    float* __restrict__ Cf, unsigned short* __restrict__ Cb,
    const long ldc, const int transC, const float* __restrict__ bias,
    const float scale, const long row0, const long col0)
{
    __shared__ __align__(16) unsigned short As[8192];   // [128][64] swizzled
    __shared__ __align__(16) unsigned short Bs[8192];

    const int tid  = threadIdx.x;
    const int lane = tid & 63;
    const int quad = lane >> 4;
    const int l16  = lane & 15;
    const int wv   = tid >> 6;
    const int wm   = (wv >> 1) * 64;
    const int wn   = (wv & 1) * 64;

    // DMA staging: chunk c = wv*256 + h*64 + lane covers row r=c>>3, linear
    // slot s=lane&7; source k-chunk j = s ^ (r&7) = (lane&7)^((lane>>3)&7).
    const int j8 = ((lane & 7) ^ ((lane >> 3) & 7)) * 8;   // src k-offset, elems
    const int rb = wv * 32 + (lane >> 3);                  // row for h=0
    const unsigned short* sa_src = Ag + (long)rb * K + j8;
    const unsigned short* sb_src = Bg + (long)rb * K + j8;
    const int dbase = (wv * 256 + lane) * 8;               // LDS dst elems, h=0

    f32x4 acc[4][4];
#pragma unroll
    for (int i = 0; i < 4; ++i)
#pragma unroll
        for (int j = 0; j < 4; ++j)
            acc[i][j] = f32x4{0.f, 0.f, 0.f, 0.f};

    // one tile = 8 DMA instructions per thread (4 A + 4 B)
    auto stage = [&](int k0) {
#pragma unroll
        for (int h = 0; h < 4; ++h) {
            async_copy16(sa_src + (long)(h * 8) * K + k0, &As[dbase + h * 512]);
            async_copy16(sb_src + (long)(h * 8) * K + k0, &Bs[dbase + h * 512]);
        }
    };

    // 32 MFMA per wave per tile (two k-halves of 32)
    auto compute = [&]() {
#pragma unroll
        for (int h = 0; h < 2; ++h) {
            bf16x8 af[4], bf[4];
            const int sl = ((quad + h * 4) ^ (l16 & 7)) * 8;
#pragma unroll
            for (int i = 0; i < 4; ++i) {
                af[i] = *(const bf16x8*)&As[(wm + i * 16 + l16) * 64 + sl];
                bf[i] = *(const bf16x8*)&Bs[(wn + i * 16 + l16) * 64 + sl];
            }
#pragma unroll
            for (int i = 0; i < 4; ++i)
#pragma unroll
                for (int j = 0; j < 4; ++j)
                    acc[i][j] = __builtin_amdgcn_mfma_f32_16x16x32_bf16(
                        af[i], bf[j], acc[i][j], 0, 0, 0);
        }
    };

    const int nk = K >> 6;            // 12 or 16
    stage(0);                         // tile 0 in flight
#pragma unroll 1
    for (int t = 0; t < nk; ++t) {
        __syncthreads();              // drains vmcnt -> tile t landed everywhere
        compute();
        __syncthreads();              // all waves done reading As/Bs
        if (t + 1 < nk) stage((t + 1) << 6);
    }

    // epilogue: C/D layout col=lane&15, row=quad*4+reg  [m89/m91 verified]
#pragma unroll
    for (int i = 0; i < 4; ++i) {
#pragma unroll
        for (int j = 0; j < 4; ++j) {
            const long r0 = row0 + wm + i * 16 + quad * 4;
            const long c  = col0 + wn + j * 16 + l16;
            const float bb = bias ? bias[c] : 0.0f;
#pragma unroll
            for (int r = 0; r < 4; ++r) {
                const float v = acc[i][j][r] * scale + bb;
                const long rr = r0 + r;
                if (Cb) {
                    if (transC) {
                        Cb[((rr >> 10) * 768 + c) * 1024 + (rr & 1023)] = f2bf(v);
                    } else {
                        Cb[rr * ldc + c] = f2bf(v);
                    }
                } else {
                    Cf[rr * ldc + c] = v;
                }
            }
        }
    }
}

// ---------------------------------------------------------------------------
// XCD-locality mapping (HW round-robins consecutive blockIdx.x over 8 XCDs).

__global__ __launch_bounds__(256, 4) void proj_qkv(
    const unsigned short* __restrict__ xb, const unsigned short* __restrict__ eb,
    const unsigned short* __restrict__ wqt, const unsigned short* __restrict__ wkt,
    const unsigned short* __restrict__ wvt,
    const float* __restrict__ bq, const float* __restrict__ bk,
    const float* __restrict__ bv,
    unsigned short* __restrict__ q, unsigned short* __restrict__ k,
    unsigned short* __restrict__ vt)
{
    const unsigned short *A, *Bt; const float* bias; unsigned short* C;
    int trans = 0;
    switch (blockIdx.z) {
        case 0:  A = xb; Bt = wqt; bias = bq; C = q;  break;
        case 1:  A = eb; Bt = wkt; bias = bk; C = k;  break;
        default: A = eb; Bt = wvt; bias = bv; C = vt; trans = 1; break;
    }
    const int p = blockIdx.x;
    const int g = p & 7, m = p >> 3;          // m in [0,48)
    const long row0 = (long)(g * 8 + (m & 7)) * 128;
    const long col0 = (long)(m >> 3) * 128;
    gemm_core(A + row0 * 768, Bt + col0 * 768, 768,
              nullptr, C, 768, trans, bias, 1.0f, row0, col0);
}

__global__ __launch_bounds__(256, 4) void scores_gemm(
    const unsigned short* __restrict__ q, const unsigned short* __restrict__ k,
    float* __restrict__ sc, float scale)
{
    const int p = blockIdx.x;                 // [0,512): batch pinned to XCD
    const long b = p & 7;
    const int m  = p >> 3;                    // [0,64)
    const long row0 = (long)(m & 7) * 128;
    const long col0 = (long)(m >> 3) * 128;
    gemm_core(q + (b * 1024 + row0) * 768, k + b * 786432 + col0 * 768, 768,
              sc + b * 1048576, nullptr, 1024, 0, nullptr, scale, row0, col0);
}

__global__ __launch_bounds__(256, 4) void pv_gemm(
    const unsigned short* __restrict__ p_, const unsigned short* __restrict__ vt,
    unsigned short* __restrict__ ao)
{
    const int p = blockIdx.x;                 // [0,384): batch pinned to XCD
    const long b = p & 7;
    const int m  = p >> 3;                    // [0,48)
    const long row0 = (long)(m & 7) * 128;
    const long col0 = (long)(m >> 3) * 128;
    gemm_core(p_ + (b * 1024 + row0) * 1024, vt + b * 786432 + col0 * 1024, 1024,
              nullptr, ao + b * 786432, 768, 0, nullptr, 1.0f, row0, col0);
}

__global__ __launch_bounds__(256, 4) void outproj_gemm(
    const unsigned short* __restrict__ ao, const unsigned short* __restrict__ wpt,
    float* __restrict__ out, const float* __restrict__ bp)
{
    const int p = blockIdx.x;                 // [0,384)
    const int g = p & 7, m = p >> 3;
    const long row0 = (long)(g * 8 + (m & 7)) * 128;
    const long col0 = (long)(m >> 3) * 128;
    gemm_core(ao + row0 * 768, wpt + col0 * 768, 768,
              out, nullptr, 768, 0, bp, 1.0f, row0, col0);
}

// ---------------------------------------------------------------------------
// prep: fp32->bf16 conversion of x/enc (blocks 0..12287) + 32x32 bf16
// transposes of the four weights (blocks 12288..14591).

__global__ __launch_bounds__(256) void prep(
    const float* __restrict__ x, const float* __restrict__ enc,
    unsigned short* __restrict__ xb, unsigned short* __restrict__ eb,
    const float* __restrict__ w0, const float* __restrict__ w1,
    const float* __restrict__ w2, const float* __restrict__ w3,
    unsigned short* __restrict__ o0, unsigned short* __restrict__ o1,
    unsigned short* __restrict__ o2, unsigned short* __restrict__ o3)
{
    __shared__ float t[32][33];
    const int bx = blockIdx.x;
    if (bx < 12288) {
        const int i = bx * 256 + threadIdx.x;   // float4 index
        const bool second = (i >= 1572864);
        const int idx = second ? i - 1572864 : i;
        const float4 v = second ? ((const float4*)enc)[idx] : ((const float4*)x)[idx];
        ushort4 o;
        o.x = f2bf(v.x); o.y = f2bf(v.y); o.z = f2bf(v.z); o.w = f2bf(v.w);
        if (second) ((ushort4*)eb)[idx] = o;
        else        ((ushort4*)xb)[idx] = o;
        return;
    }
    const int z  = bx - 12288;                  // 0..2303
    const int wi = z / 576;                     // which weight
    const int tt = z % 576;                     // 24x24 tiles
    const float* w; unsigned short* o;
    switch (wi) {
        case 0:  w = w0; o = o0; break;
        case 1:  w = w1; o = o1; break;
        case 2:  w = w2; o = o2; break;
        default: w = w3; o = o3; break;
    }
    const int tx = threadIdx.x & 31;
    const int ty = threadIdx.x >> 5;            // 0..7
    const int k0 = (tt % 24) * 32;
    const int n0 = (tt / 24) * 32;
#pragma unroll
    for (int i = 0; i < 4; ++i)
        t[ty + i * 8][tx] = w[(long)(k0 + ty + i * 8) * 768 + n0 + tx];
    __syncthreads();
#pragma unroll
    for (int i = 0; i < 4; ++i)
        o[(long)(n0 + ty + i * 8) * 768 + k0 + tx] = f2bf(t[tx][ty + i * 8]);
}

__global__ __launch_bounds__(256) void softmax_rows(
    const float* __restrict__ S, unsigned short* __restrict__ P)
{
    const long row = blockIdx.x;                 // 8192 rows of 1024
    const float* s = S + row * 1024;
    unsigned short* p = P + row * 1024;
    const int tid  = threadIdx.x;
    const int lane = tid & 63;
    const int wave = tid >> 6;

    float4 v = ((const float4*)s)[tid];
    float m = fmaxf(fmaxf(v.x, v.y), fmaxf(v.z, v.w));
#pragma unroll
    for (int off = 32; off > 0; off >>= 1)
        m = fmaxf(m, __shfl_xor(m, off));
    __shared__ float redm[4], reds[4];
    if (lane == 0) redm[wave] = m;
    __syncthreads();
    m = fmaxf(fmaxf(redm[0], redm[1]), fmaxf(redm[2], redm[3]));

    const float e0 = __expf(v.x - m), e1 = __expf(v.y - m);
    const float e2 = __expf(v.z - m), e3 = __expf(v.w - m);
    float sum = e0 + e1 + e2 + e3;
#pragma unroll
    for (int off = 32; off > 0; off >>= 1)
        sum += __shfl_xor(sum, off);
    if (lane == 0) reds[wave] = sum;
    __syncthreads();
    const float inv = 1.0f / (reds[0] + reds[1] + reds[2] + reds[3]);

    ushort4 o;
    o.x = f2bf(e0 * inv); o.y = f2bf(e1 * inv);
    o.z = f2bf(e2 * inv); o.w = f2bf(e3 * inv);
    ((ushort4*)p)[tid] = o;
}

// ---------------------------------------------------------------------------

extern "C" void kernel_launch(void* const* d_in, const int* in_sizes, int n_in,
                              void* d_out, int out_size, void* d_ws, size_t ws_size,
                              hipStream_t stream) {
    const float* x   = (const float*)d_in[0];
    const float* enc = (const float*)d_in[1];
    const float* Wq  = (const float*)d_in[2];
    const float* bq  = (const float*)d_in[3];
    const float* Wk  = (const float*)d_in[4];
    const float* bk  = (const float*)d_in[5];
    const float* Wv  = (const float*)d_in[6];
    const float* bv  = (const float*)d_in[7];
    const float* Wp  = (const float*)d_in[8];
    const float* bp  = (const float*)d_in[9];
    float* out = (float*)d_out;

    // workspace layout (bytes); peak need ~101.2 MB
    char* ws = (char*)d_ws;
    unsigned short* xb  = (unsigned short*)(ws + 0);         // 12582912
    unsigned short* eb  = (unsigned short*)(ws + 12582912);  // 12582912
    unsigned short* q   = (unsigned short*)(ws + 25165824);  // 12582912
    unsigned short* k   = (unsigned short*)(ws + 37748736);  // 12582912
    unsigned short* vt  = (unsigned short*)(ws + 50331648);  // 12582912 [B][H][S]
    unsigned short* wqt = (unsigned short*)(ws + 62914560);  // 1179648
    unsigned short* wkt = (unsigned short*)(ws + 64094208);  // 1179648
    unsigned short* wvt = (unsigned short*)(ws + 65273856);  // 1179648
    unsigned short* wpt = (unsigned short*)(ws + 66453504);  // 1179648
    float*          sc  = (float*)(ws + 67633152);           // 33554432 fp32 scores
    unsigned short* p   = (unsigned short*)(ws + 0);         // 16777216, overlays xb/eb (dead)
    unsigned short* ao  = (unsigned short*)(ws + 67633152);  // 12582912, overlays sc (dead)

    const float scale = 0.03608439182435161f;  // 1/sqrt(768)

    // 1. prep: fp32->bf16 inputs + W^T bf16 (fused)
    prep<<<14592, 256, 0, stream>>>(x, enc, xb, eb, Wq, Wk, Wv, Wp,
                                    wqt, wkt, wvt, wpt);

    // 2. q/k/v projections: 128x128 tiles, XCD-grouped flat grid
    proj_qkv<<<dim3(384, 1, 3), 256, 0, stream>>>(xb, eb, wqt, wkt, wvt,
                                                  bq, bk, bv, q, k, vt);

    // 3. scores = q k^T * scale (fp32), one batch per XCD
    scores_gemm<<<dim3(512, 1, 1), 256, 0, stream>>>(q, k, sc, scale);

    // 4. softmax rows -> bf16 P
    softmax_rows<<<8192, 256, 0, stream>>>(sc, p);

    // 5. ao = P @ V, one batch per XCD
    pv_gemm<<<dim3(384, 1, 1), 256, 0, stream>>>(p, vt, ao);

    // 6. out = ao @ Wp + bp
    outproj_gemm<<<dim3(384, 1, 1), 256, 0, stream>>>(ao, wpt, out, bp);
}